// Round 3
// baseline (39.057 us; speedup 1.0000x reference)
//
#include <hip/hip_runtime.h>
#include <hip/hip_bf16.h>
#include <math.h>

#define EMBED 128
#define VOCAB 32000
#define MEMN  50
#define BATCH 16
#define NQ    10
#define SQ    20
#define SS    40
#define BN    (BATCH*NQ)   // 160
#define NHOPS 3
#define NV    64           // vocab rows per k_out block

typedef short v8s __attribute__((ext_vector_type(8)));
typedef float v4f __attribute__((ext_vector_type(4)));

__device__ __forceinline__ short f2bf(float f) {
    __hip_bfloat16 h = __float2bfloat16(f);
    return *(short*)&h;
}

// ---- Kernel 1 (fused): query embed | story embed | H_w transpose ----
// Embedding blocks: 128 thr = 4 token-subgroups x 32 dim-quads.
// Each thread accumulates a float4 of dims over tokens s = sg + 4*i (full
// unroll -> ~20 outstanding dwordx4 gathers), then LDS-reduce across the 4
// subgroups.
__global__ void k_embed(const int* __restrict__ cq, const int* __restrict__ story,
                        const float* __restrict__ Bw, const float* __restrict__ Aw,
                        const float* __restrict__ Cw, const float* __restrict__ TA,
                        const float* __restrict__ TC, const float* __restrict__ Hw,
                        float* __restrict__ state, float* __restrict__ memb,
                        float* __restrict__ outb, float* __restrict__ HwT) {
    __shared__ int ltok[SS];
    __shared__ float4 redA[4][32];
    __shared__ float4 redC[4][32];
    int blk = blockIdx.x;
    int t = threadIdx.x;   // 128
    int sg = t >> 5;       // token subgroup 0..3
    int d4 = t & 31;       // dim quad
    int k0 = d4 << 2;      // first dim of this thread's quad

    if (blk < BN) {
        // ---- query embedding: state[bn] = sum_s Bw[cq[bn,s]] * posw(s,SQ,:)
        int bn = blk;
        if (t < SQ) ltok[t] = cq[bn * SQ + t];
        __syncthreads();
        float4 acc = {0.f, 0.f, 0.f, 0.f};
        #pragma unroll
        for (int i = 0; i < SQ / 4; ++i) {
            int s = sg + (i << 2);
            int tok = ltok[s];
            float jf = (float)(s + 1) * (1.0f / SQ);
            float c0 = 1.0f - jf;
            float c1 = (1.0f - 2.0f * jf) * (1.0f / EMBED);
            float4 a = *(const float4*)&Bw[(size_t)tok * EMBED + k0];
            acc.x += a.x * (c0 - (float)(k0 + 1) * c1);
            acc.y += a.y * (c0 - (float)(k0 + 2) * c1);
            acc.z += a.z * (c0 - (float)(k0 + 3) * c1);
            acc.w += a.w * (c0 - (float)(k0 + 4) * c1);
        }
        redA[sg][d4] = acc;
        __syncthreads();
        if (t < 32) {
            float4 s0 = redA[0][t], s1 = redA[1][t], s2 = redA[2][t], s3 = redA[3][t];
            float4 o;
            o.x = s0.x + s1.x + s2.x + s3.x;
            o.y = s0.y + s1.y + s2.y + s3.y;
            o.z = s0.z + s1.z + s2.z + s3.z;
            o.w = s0.w + s1.w + s2.w + s3.w;
            *(float4*)&state[bn * EMBED + (t << 2)] = o;
        }
    } else if (blk < BN + BATCH * MEMN) {
        // ---- story embedding: memb/outb[b,r] = sum_s {A,C}w[story[b,r,s]]*posw + T{A,C}[r]
        int br = blk - BN;
        int r = br % MEMN;
        if (t < SS) ltok[t] = story[br * SS + t];
        __syncthreads();
        float4 accA = {0.f, 0.f, 0.f, 0.f};
        float4 accC = {0.f, 0.f, 0.f, 0.f};
        #pragma unroll
        for (int i = 0; i < SS / 4; ++i) {
            int s = sg + (i << 2);
            int tok = ltok[s];
            float jf = (float)(s + 1) * (1.0f / SS);
            float c0 = 1.0f - jf;
            float c1 = (1.0f - 2.0f * jf) * (1.0f / EMBED);
            float w0 = c0 - (float)(k0 + 1) * c1;
            float w1 = c0 - (float)(k0 + 2) * c1;
            float w2 = c0 - (float)(k0 + 3) * c1;
            float w3 = c0 - (float)(k0 + 4) * c1;
            float4 a = *(const float4*)&Aw[(size_t)tok * EMBED + k0];
            float4 c = *(const float4*)&Cw[(size_t)tok * EMBED + k0];
            accA.x += a.x * w0; accA.y += a.y * w1; accA.z += a.z * w2; accA.w += a.w * w3;
            accC.x += c.x * w0; accC.y += c.y * w1; accC.z += c.z * w2; accC.w += c.w * w3;
        }
        redA[sg][d4] = accA;
        redC[sg][d4] = accC;
        __syncthreads();
        if (t < 32) {
            float4 s0 = redA[0][t], s1 = redA[1][t], s2 = redA[2][t], s3 = redA[3][t];
            float4 ta = *(const float4*)&TA[r * EMBED + (t << 2)];
            float4 o;
            o.x = s0.x + s1.x + s2.x + s3.x + ta.x;
            o.y = s0.y + s1.y + s2.y + s3.y + ta.y;
            o.z = s0.z + s1.z + s2.z + s3.z + ta.z;
            o.w = s0.w + s1.w + s2.w + s3.w + ta.w;
            *(float4*)&memb[br * EMBED + (t << 2)] = o;
        } else if (t < 64) {
            int u = t - 32;
            float4 s0 = redC[0][u], s1 = redC[1][u], s2 = redC[2][u], s3 = redC[3][u];
            float4 tc = *(const float4*)&TC[r * EMBED + (u << 2)];
            float4 o;
            o.x = s0.x + s1.x + s2.x + s3.x + tc.x;
            o.y = s0.y + s1.y + s2.y + s3.y + tc.y;
            o.z = s0.z + s1.z + s2.z + s3.z + tc.z;
            o.w = s0.w + s1.w + s2.w + s3.w + tc.w;
            *(float4*)&outb[br * EMBED + (u << 2)] = o;
        }
    } else {
        int k = blk - (BN + BATCH * MEMN);
        HwT[k * EMBED + t] = Hw[t * EMBED + k];
    }
}

// ---- Kernel 2: 3 hops, one block per query; outputs state as bf16 ----
__global__ void k_hops(const float* __restrict__ memb, const float* __restrict__ outb,
                       const float* __restrict__ HwT, const float* __restrict__ Hb,
                       const float* __restrict__ state, __hip_bfloat16* __restrict__ stateb) {
    __shared__ float lmem[MEMN][EMBED + 1];
    __shared__ float lout[MEMN][EMBED + 1];
    __shared__ float lstate[EMBED];
    __shared__ float lprobs[MEMN];
    __shared__ float lresp[EMBED];
    int bn = blockIdx.x;
    int b  = bn / NQ;
    int t  = threadIdx.x;   // 128
    for (int i = t; i < MEMN * EMBED; i += EMBED) {
        int r = i >> 7, d = i & 127;
        lmem[r][d] = memb[b * MEMN * EMBED + i];
        lout[r][d] = outb[b * MEMN * EMBED + i];
    }
    lstate[t] = state[bn * EMBED + t];
    __syncthreads();

    for (int hop = 0; hop < NHOPS; ++hop) {
        float logit = -1e30f;
        if (t < MEMN) {
            float acc = 0.f;
            #pragma unroll 8
            for (int d = 0; d < EMBED; ++d) acc += lmem[t][d] * lstate[d];
            logit = acc;
        }
        if (t < 64) {
            float m = logit;
            #pragma unroll
            for (int off = 32; off; off >>= 1) m = fmaxf(m, __shfl_xor(m, off, 64));
            float e = (t < MEMN) ? __expf(logit - m) : 0.f;
            float ssum = e;
            #pragma unroll
            for (int off = 32; off; off >>= 1) ssum += __shfl_xor(ssum, off, 64);
            if (t < MEMN) lprobs[t] = e / ssum;
        }
        __syncthreads();
        float resp = 0.f;
        #pragma unroll 10
        for (int r = 0; r < MEMN; ++r) resp += lprobs[r] * lout[r][t];
        lresp[t] = resp;
        __syncthreads();
        float acc = Hb[t] + lstate[t];
        #pragma unroll 8
        for (int k = 0; k < EMBED; ++k) acc += lresp[k] * HwT[k * EMBED + t];
        __syncthreads();
        lstate[t] = acc;
        __syncthreads();
    }
    stateb[bn * EMBED + t] = __float2bfloat16(lstate[t]);
}

// ---- Kernel 3: out[160,32000] = state_bf16 @ W^T via MFMA 16x16x32 ----
__global__ __launch_bounds__(256) void k_out(const __hip_bfloat16* __restrict__ stateb,
                                             const float* __restrict__ outw,
                                             float* __restrict__ out) {
    __shared__ __align__(16) __hip_bfloat16 Alds[BN][EMBED + 8];   // 160 x 136
    __shared__ __align__(16) __hip_bfloat16 Blds[NV][EMBED + 8];   // 64 x 136
    int t = threadIdx.x;
    int vbase = blockIdx.x * NV;

    #pragma unroll
    for (int i = 0; i < 10; ++i) {
        int e = t + i * 256;           // 0..2559
        int row = e >> 4, c8 = (e & 15) << 3;
        *(int4*)&Alds[row][c8] = *(const int4*)&stateb[row * EMBED + c8];
    }
    #pragma unroll
    for (int i = 0; i < 8; ++i) {
        int e = t + i * 256;           // 0..2047
        int row = e >> 5, c4 = (e & 31) << 2;
        float4 w = *(const float4*)&outw[(size_t)(vbase + row) * EMBED + c4];
        short4 p;
        p.x = f2bf(w.x); p.y = f2bf(w.y); p.z = f2bf(w.z); p.w = f2bf(w.w);
        *(short4*)&Blds[row][c4] = p;
    }
    __syncthreads();

    int wv = t >> 6;                  // wave id: N-tile
    int l = t & 63;
    int col16 = l & 15;
    int kg = l >> 4;                  // k-group 0..3

    v8s bfrag[4];
    #pragma unroll
    for (int k4 = 0; k4 < 4; ++k4)
        bfrag[k4] = *(v8s*)&Blds[(wv << 4) + col16][k4 * 32 + kg * 8];

    v4f acc[10];
    #pragma unroll
    for (int m = 0; m < 10; ++m) acc[m] = (v4f){0.f, 0.f, 0.f, 0.f};

    #pragma unroll
    for (int k4 = 0; k4 < 4; ++k4) {
        #pragma unroll
        for (int m = 0; m < 10; ++m) {
            v8s af = *(v8s*)&Alds[m * 16 + col16][k4 * 32 + kg * 8];
            acc[m] = __builtin_amdgcn_mfma_f32_16x16x32_bf16(af, bfrag[k4], acc[m], 0, 0, 0);
        }
    }

    int colg = vbase + (wv << 4) + col16;
    #pragma unroll
    for (int m = 0; m < 10; ++m) {
        #pragma unroll
        for (int i = 0; i < 4; ++i) {
            out[(size_t)(m * 16 + kg * 4 + i) * VOCAB + colg] = acc[m][i];
        }
    }
}

extern "C" void kernel_launch(void* const* d_in, const int* in_sizes, int n_in,
                              void* d_out, int out_size, void* d_ws, size_t ws_size,
                              hipStream_t stream) {
    const int*   ctx_query = (const int*)  d_in[0];
    const int*   story     = (const int*)  d_in[1];
    const float* A_w       = (const float*)d_in[2];
    const float* C_w       = (const float*)d_in[3];
    const float* B_w       = (const float*)d_in[4];
    const float* H_w       = (const float*)d_in[5];
    const float* H_b       = (const float*)d_in[6];
    const float* out_w     = (const float*)d_in[7];
    const float* TA        = (const float*)d_in[8];
    const float* TC        = (const float*)d_in[9];
    float* out = (float*)d_out;

    float* ws    = (float*)d_ws;
    float* state = ws;                                   // 160*128 f32
    float* memb  = state + BN * EMBED;                   // 16*50*128
    float* outb  = memb + BATCH * MEMN * EMBED;          // 16*50*128
    float* HwT   = outb + BATCH * MEMN * EMBED;          // 128*128
    __hip_bfloat16* stateb = (__hip_bfloat16*)(HwT + EMBED * EMBED);  // 160*128 bf16

    k_embed<<<BN + BATCH * MEMN + EMBED, 128, 0, stream>>>(
        ctx_query, story, B_w, A_w, C_w, TA, TC, H_w, state, memb, outb, HwT);
    k_hops<<<BN, EMBED, 0, stream>>>(memb, outb, HwT, H_b, state, stateb);
    k_out<<<VOCAB / NV, 256, 0, stream>>>(stateb, out_w, out);
}

// Round 4
// 36.784 us; speedup vs baseline: 1.0618x; 1.0618x over previous
//
#include <hip/hip_runtime.h>
#include <hip/hip_bf16.h>
#include <math.h>

#define EMBED 128
#define VOCAB 32000
#define MEMN  50
#define BATCH 16
#define NQ    10
#define SQ    20
#define SS    40
#define BN    (BATCH*NQ)   // 160
#define NHOPS 3

typedef short v8s __attribute__((ext_vector_type(8)));
typedef float v4f __attribute__((ext_vector_type(4)));

__device__ __forceinline__ float posw(int j, int J, int k) {
    float jf = (float)(j + 1) / (float)J;
    return 1.0f - jf - ((float)(k + 1) / (float)EMBED) * (1.0f - 2.0f * jf);
}

__device__ __forceinline__ short f2bf(float f) {
    __hip_bfloat16 h = __float2bfloat16(f);
    return *(short*)&h;
}

// ---- Kernel 1 (fused): query embed | story embed | H_w transpose ----
// (exact R2 form — proven 35.4 us baseline)
__global__ void k_embed(const int* __restrict__ cq, const int* __restrict__ story,
                        const float* __restrict__ Bw, const float* __restrict__ Aw,
                        const float* __restrict__ Cw, const float* __restrict__ TA,
                        const float* __restrict__ TC, const float* __restrict__ Hw,
                        float* __restrict__ state, float* __restrict__ memb,
                        float* __restrict__ outb, float* __restrict__ HwT) {
    int blk = blockIdx.x;
    int t = threadIdx.x;   // 128
    if (blk < BN) {
        float acc = 0.f;
        #pragma unroll
        for (int s = 0; s < SQ; ++s) {
            int tok = cq[blk * SQ + s];
            acc += Bw[tok * EMBED + t] * posw(s, SQ, t);
        }
        state[blk * EMBED + t] = acc;
    } else if (blk < BN + BATCH * MEMN) {
        int br = blk - BN;
        int r = br % MEMN;
        float ma = TA[r * EMBED + t];
        float mc = TC[r * EMBED + t];
        const int* toks = story + br * SS;
        #pragma unroll 4
        for (int s = 0; s < SS; ++s) {
            int tok = toks[s];
            float w = posw(s, SS, t);
            ma += Aw[tok * EMBED + t] * w;
            mc += Cw[tok * EMBED + t] * w;
        }
        memb[br * EMBED + t] = ma;
        outb[br * EMBED + t] = mc;
    } else {
        int k = blk - (BN + BATCH * MEMN);
        HwT[k * EMBED + t] = Hw[t * EMBED + k];
    }
}

// ---- Kernel 2: 3 hops; epilogue stores state in MFMA A-fragment layout ----
// stateF layout: [(k4*4+kg)][row(160)][8 elems]  (bf16, 16B chunks)
__global__ void k_hops(const float* __restrict__ memb, const float* __restrict__ outb,
                       const float* __restrict__ HwT, const float* __restrict__ Hb,
                       const float* __restrict__ state, __hip_bfloat16* __restrict__ stateF) {
    __shared__ float lmem[MEMN][EMBED + 1];
    __shared__ float lout[MEMN][EMBED + 1];
    __shared__ float lstate[EMBED];
    __shared__ float lprobs[MEMN];
    __shared__ float lresp[EMBED];
    int bn = blockIdx.x;
    int b  = bn / NQ;
    int t  = threadIdx.x;   // 128
    for (int i = t; i < MEMN * EMBED; i += EMBED) {
        int r = i >> 7, d = i & 127;
        lmem[r][d] = memb[b * MEMN * EMBED + i];
        lout[r][d] = outb[b * MEMN * EMBED + i];
    }
    lstate[t] = state[bn * EMBED + t];
    __syncthreads();

    for (int hop = 0; hop < NHOPS; ++hop) {
        float logit = -1e30f;
        if (t < MEMN) {
            float acc = 0.f;
            for (int d = 0; d < EMBED; ++d) acc += lmem[t][d] * lstate[d];
            logit = acc;
        }
        if (t < 64) {
            float m = logit;
            #pragma unroll
            for (int off = 32; off; off >>= 1) m = fmaxf(m, __shfl_xor(m, off, 64));
            float e = (t < MEMN) ? __expf(logit - m) : 0.f;
            float ssum = e;
            #pragma unroll
            for (int off = 32; off; off >>= 1) ssum += __shfl_xor(ssum, off, 64);
            if (t < MEMN) lprobs[t] = e / ssum;
        }
        __syncthreads();
        float resp = 0.f;
        for (int r = 0; r < MEMN; ++r) resp += lprobs[r] * lout[r][t];
        lresp[t] = resp;
        __syncthreads();
        float acc = Hb[t] + lstate[t];
        for (int k = 0; k < EMBED; ++k) acc += lresp[k] * HwT[k * EMBED + t];
        __syncthreads();
        lstate[t] = acc;
        __syncthreads();
    }
    // d = t: k4 = d>>5, kg = (d>>3)&3, e = d&7
    int frag = ((t >> 5) << 2) | ((t >> 3) & 3);
    stateF[((size_t)frag * BN + bn) * 8 + (t & 7)] = __float2bfloat16(lstate[t]);
}

// ---- Kernel 3: out[160,32000] = state @ W^T. Zero-LDS streaming MFMA. ----
// 2000 blocks x 64 threads (one wave). Each wave: 16 vocab cols, all 160 bn.
__global__ __launch_bounds__(64) void k_out(const __hip_bfloat16* __restrict__ stateF,
                                            const float* __restrict__ outw,
                                            float* __restrict__ out) {
    int l = threadIdx.x;              // 0..63
    int col16 = l & 15;
    int kg = l >> 4;                  // 0..3
    int vbase = blockIdx.x << 4;
    int v = vbase + col16;            // this lane's vocab row (B-operand col)

    // B fragments: per k4, 8 consecutive f32 of outw row v at k = k4*32+kg*8.
    // Per instruction, 16 rows x 128B contiguous chunks — line-granular coalescing.
    v8s bfrag[4];
    #pragma unroll
    for (int k4 = 0; k4 < 4; ++k4) {
        const float4* p = (const float4*)&outw[(size_t)v * EMBED + k4 * 32 + kg * 8];
        float4 w0 = p[0], w1 = p[1];
        v8s bf;
        bf[0] = f2bf(w0.x); bf[1] = f2bf(w0.y); bf[2] = f2bf(w0.z); bf[3] = f2bf(w0.w);
        bf[4] = f2bf(w1.x); bf[5] = f2bf(w1.y); bf[6] = f2bf(w1.z); bf[7] = f2bf(w1.w);
        bfrag[k4] = bf;
    }

    v4f acc[10];
    #pragma unroll
    for (int m = 0; m < 10; ++m) acc[m] = (v4f){0.f, 0.f, 0.f, 0.f};

    // A fragments stream from L2-hot stateF (40KB): 16 lanes x 16B = 256B/instr.
    const v8s* aF = (const v8s*)stateF;
    #pragma unroll
    for (int k4 = 0; k4 < 4; ++k4) {
        v8s af[10];
        #pragma unroll
        for (int m = 0; m < 10; ++m)
            af[m] = aF[(((k4 << 2) | kg) * BN) + m * 16 + col16];
        #pragma unroll
        for (int m = 0; m < 10; ++m)
            acc[m] = __builtin_amdgcn_mfma_f32_16x16x32_bf16(af[m], bfrag[k4], acc[m], 0, 0, 0);
    }

    #pragma unroll
    for (int m = 0; m < 10; ++m) {
        #pragma unroll
        for (int i = 0; i < 4; ++i)
            out[(size_t)(m * 16 + kg * 4 + i) * VOCAB + v] = acc[m][i];
    }
}

extern "C" void kernel_launch(void* const* d_in, const int* in_sizes, int n_in,
                              void* d_out, int out_size, void* d_ws, size_t ws_size,
                              hipStream_t stream) {
    const int*   ctx_query = (const int*)  d_in[0];
    const int*   story     = (const int*)  d_in[1];
    const float* A_w       = (const float*)d_in[2];
    const float* C_w       = (const float*)d_in[3];
    const float* B_w       = (const float*)d_in[4];
    const float* H_w       = (const float*)d_in[5];
    const float* H_b       = (const float*)d_in[6];
    const float* out_w     = (const float*)d_in[7];
    const float* TA        = (const float*)d_in[8];
    const float* TC        = (const float*)d_in[9];
    float* out = (float*)d_out;

    float* ws    = (float*)d_ws;
    float* state = ws;                                   // 160*128 f32
    float* memb  = state + BN * EMBED;                   // 16*50*128
    float* outb  = memb + BATCH * MEMN * EMBED;          // 16*50*128
    float* HwT   = outb + BATCH * MEMN * EMBED;          // 128*128
    __hip_bfloat16* stateF = (__hip_bfloat16*)(HwT + EMBED * EMBED);  // 16 frags x 160 x 8 bf16

    k_embed<<<BN + BATCH * MEMN + EMBED, EMBED, 0, stream>>>(
        ctx_query, story, B_w, A_w, C_w, TA, TC, H_w, state, memb, outb, HwT);
    k_hops<<<BN, EMBED, 0, stream>>>(memb, outb, HwT, H_b, state, stateF);
    k_out<<<VOCAB / 16, 64, 0, stream>>>(stateF, out_w, out);
}

// Round 5
// 35.872 us; speedup vs baseline: 1.0888x; 1.0254x over previous
//
#include <hip/hip_runtime.h>
#include <hip/hip_bf16.h>
#include <math.h>

#define EMBED 128
#define VOCAB 32000
#define MEMN  50
#define BATCH 16
#define NQ    10
#define SQ    20
#define SS    40
#define BN    (BATCH*NQ)   // 160
#define NHOPS 3

// k_embed grid sections
#define G_QRY   BN                    // [0,160): query embed
#define G_STA   (G_QRY + BATCH*MEMN)  // [160,960): story A
#define G_STC   (G_STA + BATCH*MEMN)  // [960,1760): story C
#define G_HT    (G_STC + EMBED)       // [1760,1888): H transpose
#define CONVROWS 64
#define G_CONV  (G_HT + VOCAB/CONVROWS) // [1888,2388): out_w -> bf16

typedef short v8s __attribute__((ext_vector_type(8)));
typedef float v4f __attribute__((ext_vector_type(4)));

__device__ __forceinline__ float posw(int j, int J, int k) {
    float jf = (float)(j + 1) / (float)J;
    return 1.0f - jf - ((float)(k + 1) / (float)EMBED) * (1.0f - 2.0f * jf);
}

__device__ __forceinline__ short f2bf(float f) {
    __hip_bfloat16 h = __float2bfloat16(f);
    return *(short*)&h;
}

// ---- Kernel 1 (fused): query | storyA | storyC | H^T | out_w->bf16 ----
__global__ void k_embed(const int* __restrict__ cq, const int* __restrict__ story,
                        const float* __restrict__ Bw, const float* __restrict__ Aw,
                        const float* __restrict__ Cw, const float* __restrict__ TA,
                        const float* __restrict__ TC, const float* __restrict__ Hw,
                        const float* __restrict__ outw,
                        float* __restrict__ state, float* __restrict__ memb,
                        float* __restrict__ outb, float* __restrict__ HwT,
                        __hip_bfloat16* __restrict__ owb) {
    int blk = blockIdx.x;
    int t = threadIdx.x;   // 128
    if (blk < G_QRY) {
        // query embedding: full unroll -> all 20 token loads + 20 gathers in flight
        float acc = 0.f;
        const int* toks = cq + blk * SQ;
        #pragma unroll
        for (int s = 0; s < SQ; ++s) {
            int tok = toks[s];
            acc += Bw[tok * EMBED + t] * posw(s, SQ, t);
        }
        state[blk * EMBED + t] = acc;
    } else if (blk < G_STA) {
        // story A-table: one block per (b,r); full unroll -> 40 gathers in flight
        int br = blk - G_QRY;
        int r = br % MEMN;
        float ma = TA[r * EMBED + t];
        const int* toks = story + br * SS;
        #pragma unroll
        for (int s = 0; s < SS; ++s) {
            int tok = toks[s];
            ma += Aw[tok * EMBED + t] * posw(s, SS, t);
        }
        memb[br * EMBED + t] = ma;
    } else if (blk < G_STC) {
        // story C-table
        int br = blk - G_STA;
        int r = br % MEMN;
        float mc = TC[r * EMBED + t];
        const int* toks = story + br * SS;
        #pragma unroll
        for (int s = 0; s < SS; ++s) {
            int tok = toks[s];
            mc += Cw[tok * EMBED + t] * posw(s, SS, t);
        }
        outb[br * EMBED + t] = mc;
    } else if (blk < G_HT) {
        int k = blk - G_STC;
        HwT[k * EMBED + t] = Hw[t * EMBED + k];
    } else {
        // out_w f32 -> bf16 (64 vocab rows per block): streams on idle BW
        int base = (blk - G_HT) * (CONVROWS * EMBED);
        #pragma unroll
        for (int i = 0; i < 16; ++i) {
            int e = base + i * 512 + t * 4;
            float4 w = *(const float4*)&outw[e];
            short4 p;
            p.x = f2bf(w.x); p.y = f2bf(w.y); p.z = f2bf(w.z); p.w = f2bf(w.w);
            *(short4*)&owb[e] = p;
        }
    }
}

// ---- Kernel 2: 3 hops; epilogue stores state in MFMA A-fragment layout ----
__global__ void k_hops(const float* __restrict__ memb, const float* __restrict__ outb,
                       const float* __restrict__ HwT, const float* __restrict__ Hb,
                       const float* __restrict__ state, __hip_bfloat16* __restrict__ stateF) {
    __shared__ float lmem[MEMN][EMBED + 1];
    __shared__ float lout[MEMN][EMBED + 1];
    __shared__ float lstate[EMBED];
    __shared__ float lprobs[MEMN];
    __shared__ float lresp[EMBED];
    int bn = blockIdx.x;
    int b  = bn / NQ;
    int t  = threadIdx.x;   // 128
    #pragma unroll
    for (int i = 0; i < MEMN; ++i) {
        int e = i * EMBED + t;
        lmem[i][t] = memb[b * MEMN * EMBED + e];
        lout[i][t] = outb[b * MEMN * EMBED + e];
    }
    lstate[t] = state[bn * EMBED + t];
    __syncthreads();

    for (int hop = 0; hop < NHOPS; ++hop) {
        float logit = -1e30f;
        if (t < MEMN) {
            float acc = 0.f;
            for (int d = 0; d < EMBED; ++d) acc += lmem[t][d] * lstate[d];
            logit = acc;
        }
        if (t < 64) {
            float m = logit;
            #pragma unroll
            for (int off = 32; off; off >>= 1) m = fmaxf(m, __shfl_xor(m, off, 64));
            float e = (t < MEMN) ? __expf(logit - m) : 0.f;
            float ssum = e;
            #pragma unroll
            for (int off = 32; off; off >>= 1) ssum += __shfl_xor(ssum, off, 64);
            if (t < MEMN) lprobs[t] = e / ssum;
        }
        __syncthreads();
        float resp = 0.f;
        for (int r = 0; r < MEMN; ++r) resp += lprobs[r] * lout[r][t];
        lresp[t] = resp;
        __syncthreads();
        float acc = Hb[t] + lstate[t];
        for (int k = 0; k < EMBED; ++k) acc += lresp[k] * HwT[k * EMBED + t];
        __syncthreads();
        lstate[t] = acc;
        __syncthreads();
    }
    // d = t: k4 = d>>5, kg = (d>>3)&3, e = d&7
    int frag = ((t >> 5) << 2) | ((t >> 3) & 3);
    stateF[((size_t)frag * BN + bn) * 8 + (t & 7)] = __float2bfloat16(lstate[t]);
}

// ---- Kernel 3: out[160,32000] = state @ W^T. Zero-LDS streaming MFMA. ----
__global__ __launch_bounds__(64) void k_out(const __hip_bfloat16* __restrict__ stateF,
                                            const __hip_bfloat16* __restrict__ owb,
                                            float* __restrict__ out) {
    int l = threadIdx.x;              // 0..63
    int col16 = l & 15;
    int kg = l >> 4;                  // 0..3
    int vbase = blockIdx.x << 4;
    int v = vbase + col16;

    // B fragments: direct v8s loads from pre-converted bf16 weights
    const v8s* bp = (const v8s*)owb;  // row v = 16 v8s chunks
    v8s bfrag[4];
    #pragma unroll
    for (int k4 = 0; k4 < 4; ++k4)
        bfrag[k4] = bp[(size_t)v * 16 + k4 * 4 + kg];

    v4f acc[10];
    #pragma unroll
    for (int m = 0; m < 10; ++m) acc[m] = (v4f){0.f, 0.f, 0.f, 0.f};

    const v8s* aF = (const v8s*)stateF;
    #pragma unroll
    for (int k4 = 0; k4 < 4; ++k4) {
        v8s af[10];
        #pragma unroll
        for (int m = 0; m < 10; ++m)
            af[m] = aF[(((k4 << 2) | kg) * BN) + m * 16 + col16];
        #pragma unroll
        for (int m = 0; m < 10; ++m)
            acc[m] = __builtin_amdgcn_mfma_f32_16x16x32_bf16(af[m], bfrag[k4], acc[m], 0, 0, 0);
    }

    #pragma unroll
    for (int m = 0; m < 10; ++m) {
        #pragma unroll
        for (int i = 0; i < 4; ++i)
            out[(size_t)(m * 16 + kg * 4 + i) * VOCAB + v] = acc[m][i];
    }
}

extern "C" void kernel_launch(void* const* d_in, const int* in_sizes, int n_in,
                              void* d_out, int out_size, void* d_ws, size_t ws_size,
                              hipStream_t stream) {
    const int*   ctx_query = (const int*)  d_in[0];
    const int*   story     = (const int*)  d_in[1];
    const float* A_w       = (const float*)d_in[2];
    const float* C_w       = (const float*)d_in[3];
    const float* B_w       = (const float*)d_in[4];
    const float* H_w       = (const float*)d_in[5];
    const float* H_b       = (const float*)d_in[6];
    const float* out_w     = (const float*)d_in[7];
    const float* TA        = (const float*)d_in[8];
    const float* TC        = (const float*)d_in[9];
    float* out = (float*)d_out;

    float* ws    = (float*)d_ws;
    float* state = ws;                                   // 160*128 f32
    float* memb  = state + BN * EMBED;                   // 16*50*128
    float* outb  = memb + BATCH * MEMN * EMBED;          // 16*50*128
    float* HwT   = outb + BATCH * MEMN * EMBED;          // 128*128
    __hip_bfloat16* stateF = (__hip_bfloat16*)(HwT + EMBED * EMBED);   // 160*128 bf16
    __hip_bfloat16* owb    = stateF + BN * EMBED;        // 32000*128 bf16

    k_embed<<<G_CONV, 128, 0, stream>>>(
        ctx_query, story, B_w, A_w, C_w, TA, TC, H_w, out_w,
        state, memb, outb, HwT, owb);
    k_hops<<<BN, 128, 0, stream>>>(memb, outb, HwT, H_b, state, stateF);
    k_out<<<VOCAB / 16, 64, 0, stream>>>(stateF, owb, out);
}